// Round 16
// baseline (502.431 us; speedup 1.0000x reference)
//
#include <hip/hip_runtime.h>
#include <hip/hip_bf16.h>
#include <hip/hip_cooperative_groups.h>
#include <math.h>

namespace cg = cooperative_groups;

typedef __attribute__((ext_vector_type(8))) short bf16x8;
typedef __attribute__((ext_vector_type(4))) float f32x4;

static __device__ __forceinline__ unsigned short f2bf(float f) {
    union { float f; unsigned int u; } x{f};
    unsigned int u = x.u;
    unsigned int r = (u + 0x7fffu + ((u >> 16) & 1u)) >> 16;  // RNE
    return (unsigned short)r;
}

static __device__ __forceinline__ unsigned int pack2(float f0, float f1) {
    __hip_bfloat162 h = __float22bfloat162_rn(float2{f0, f1});
    union { __hip_bfloat162 h; unsigned int u; } c{h};
    return c.u;
}

// ---------------------------------------------------------------------------
// Stage 0+4a: graph branch + wprep as block B (R13/R14 proven).
// ---------------------------------------------------------------------------
__global__ __launch_bounds__(640, 1) void graph_wprep(
    const float* __restrict__ conv_w, unsigned short* __restrict__ wB,
    const float* __restrict__ nfeat, const int* __restrict__ eidx,
    const float* __restrict__ e1w, const float* __restrict__ e1b,
    const float* __restrict__ e2w, const float* __restrict__ e2b,
    const float* __restrict__ gcw, const float* __restrict__ gcb,
    const float* __restrict__ lns, const float* __restrict__ lnb,
    const float* __restrict__ pjw, const float* __restrict__ pjb,
    const float* __restrict__ a1w, const float* __restrict__ a1b,
    const float* __restrict__ a2w, const float* __restrict__ a2b,
    float* __restrict__ gts_g, float* __restrict__ rtok, int B) {
    __shared__ __align__(16) float pool[8448];
    __shared__ __align__(16) float nf[10][20];
    __shared__ __align__(16) float xsA[10][64];
    __shared__ __align__(16) float xsB[10][64];
    __shared__ __align__(16) float nbs[10][64];
    __shared__ __align__(16) float gtss[10][32];
    __shared__ float svs[10];
    __shared__ int se[18], de[18];
    const int t = threadIdx.x;
    const int b = blockIdx.x;
    const int n = t >> 6, o = t & 63;

    if (b == B) {
        for (int idx = t; idx < 24 * 32 * 8; idx += 640) {
            int s = idx >> 8;
            int ch = (idx >> 3) & 31;
            int kx = idx & 7;
            int c = s >> 3, ky = s & 7;
            float v = 0.f;
            if (ky < 7 && kx < 7) v = conv_w[ch * 147 + c * 49 + ky * 7 + kx];
            wB[idx] = f2bf(v);
        }
        return;
    }

    if (t < 190) {
        int nn = t / 19, i = t - nn * 19;
        nf[nn][i] = nfeat[(size_t)(b * 10 + nn) * 19 + i];
    }
    if (t < 36) {
        if (t < 18) se[t] = eidx[b * 36 + t];
        else de[t - 18] = eidx[b * 36 + t];
    }
    float* e1wT = pool;
    float* e2wT = pool + 1280;
    for (int u = t; u < 1216; u += 640) {
        int oo = u / 19, k = u - oo * 19;
        e1wT[k * 64 + oo] = e1w[u];
    }
    for (int u = t; u < 4096; u += 640) {
        int oo = u >> 6, k = u & 63;
        e2wT[k * 65 + oo] = e2w[u];
    }
    __syncthreads();

    {
        float acc = e1b[o];
#pragma unroll
        for (int i = 0; i < 19; ++i) acc = fmaf(nf[n][i], e1wT[i * 64 + o], acc);
        xsB[n][o] = fmaxf(acc, 0.f);
    }
    {
        const float* xrow = &xsB[n][0];
        float s0 = 0, s1 = 0, s2 = 0, s3 = 0;
#pragma unroll
        for (int k = 0; k < 64; k += 4) {
            s0 = fmaf(xrow[k], e2wT[k * 65 + o], s0);
            s1 = fmaf(xrow[k + 1], e2wT[(k + 1) * 65 + o], s1);
            s2 = fmaf(xrow[k + 2], e2wT[(k + 2) * 65 + o], s2);
            s3 = fmaf(xrow[k + 3], e2wT[(k + 3) * 65 + o], s3);
        }
        xsA[n][o] = e2b[o] + ((s0 + s1) + (s2 + s3));
    }
    __syncthreads();

    float* src = &xsA[0][0];
    float* dst = &xsB[0][0];
    for (int l = 0; l < 3; ++l) {
        const float* gl = gcw + (size_t)l * 8192;
        for (int u = t; u < 8192; u += 640) {
            int oo = u >> 7, k = u & 127;
            pool[k * 65 + oo] = gl[u];
        }
        {
            float s = 0.f;
            int cnt = 0;
#pragma unroll
            for (int e = 0; e < 18; ++e) {
                bool m = (de[e] == n);
                float v = src[se[e] * 64 + o];
                s += m ? v : 0.f;
                cnt += m ? 1 : 0;
            }
            nbs[n][o] = s / (float)(cnt > 1 ? cnt : 1);
        }
        __syncthreads();
        {
            const float* xa = src + n * 64;
            const float* xb = &nbs[n][0];
            float s0 = 0, s1 = 0, s2 = 0, s3 = 0;
#pragma unroll
            for (int k = 0; k < 64; k += 4) {
                s0 = fmaf(xa[k], pool[k * 65 + o], s0);
                s1 = fmaf(xa[k + 1], pool[(k + 1) * 65 + o], s1);
                s2 = fmaf(xa[k + 2], pool[(k + 2) * 65 + o], s2);
                s3 = fmaf(xa[k + 3], pool[(k + 3) * 65 + o], s3);
            }
#pragma unroll
            for (int k = 0; k < 64; k += 4) {
                s0 = fmaf(xb[k], pool[(64 + k) * 65 + o], s0);
                s1 = fmaf(xb[k + 1], pool[(64 + k + 1) * 65 + o], s1);
                s2 = fmaf(xb[k + 2], pool[(64 + k + 2) * 65 + o], s2);
                s3 = fmaf(xb[k + 3], pool[(64 + k + 3) * 65 + o], s3);
            }
            float v = gcb[l * 64 + o] + ((s0 + s1) + (s2 + s3)) + xa[o];
            float mu = v;
            mu += __shfl_xor(mu, 32);
            mu += __shfl_xor(mu, 16);
            mu += __shfl_xor(mu, 8);
            mu += __shfl_xor(mu, 4);
            mu += __shfl_xor(mu, 2);
            mu += __shfl_xor(mu, 1);
            mu *= (1.f / 64.f);
            float d = v - mu;
            float vr = d * d;
            vr += __shfl_xor(vr, 32);
            vr += __shfl_xor(vr, 16);
            vr += __shfl_xor(vr, 8);
            vr += __shfl_xor(vr, 4);
            vr += __shfl_xor(vr, 2);
            vr += __shfl_xor(vr, 1);
            vr *= (1.f / 64.f);
            dst[n * 64 + o] =
                fmaxf(d / sqrtf(vr + 1e-5f) * lns[l * 64 + o] + lnb[l * 64 + o], 0.f);
        }
        __syncthreads();
        float* tmp = src;
        src = dst;
        dst = tmp;
    }

    float* pjwT = pool;
    float* a1wT = pool + 2112;
    for (int u = t; u < 2048; u += 640) {
        int oo = u >> 6, k = u & 63;
        pjwT[k * 33 + oo] = pjw[u];
    }
    for (int u = t; u < 512; u += 640) {
        int hh = u >> 5, k = u & 31;
        a1wT[k * 17 + hh] = a1w[u];
    }
    __syncthreads();

    if (o < 32) {
        const float* xrow = src + n * 64;
        float s0 = 0, s1 = 0, s2 = 0, s3 = 0;
#pragma unroll
        for (int k = 0; k < 64; k += 4) {
            s0 = fmaf(xrow[k], pjwT[k * 33 + o], s0);
            s1 = fmaf(xrow[k + 1], pjwT[(k + 1) * 33 + o], s1);
            s2 = fmaf(xrow[k + 2], pjwT[(k + 2) * 33 + o], s2);
            s3 = fmaf(xrow[k + 3], pjwT[(k + 3) * 33 + o], s3);
        }
        float gv = pjb[o] + ((s0 + s1) + (s2 + s3));
        gtss[n][o] = gv;
        gts_g[(size_t)b * 320 + n * 32 + o] = gv;
    }
    if (o < 16) {
        const float* xrow = &gtss[n][0];
        float s0 = 0, s1 = 0, s2 = 0, s3 = 0;
#pragma unroll
        for (int k = 0; k < 32; k += 4) {
            s0 = fmaf(xrow[k], a1wT[k * 17 + o], s0);
            s1 = fmaf(xrow[k + 1], a1wT[(k + 1) * 17 + o], s1);
            s2 = fmaf(xrow[k + 2], a1wT[(k + 2) * 17 + o], s2);
            s3 = fmaf(xrow[k + 3], a1wT[(k + 3) * 17 + o], s3);
        }
        float z = a1b[o] + ((s0 + s1) + (s2 + s3));
        float sc = tanhf(z) * a2w[o];
        sc += __shfl_xor(sc, 8);
        sc += __shfl_xor(sc, 4);
        sc += __shfl_xor(sc, 2);
        sc += __shfl_xor(sc, 1);
        if (o == 0) svs[n] = sc + a2b[0];
    }
    __syncthreads();

    if (n == 0 && o < 32) {
        float m = svs[0];
#pragma unroll
        for (int i = 1; i < 10; ++i) m = fmaxf(m, svs[i]);
        float e[10];
        float sum = 0.f;
#pragma unroll
        for (int i = 0; i < 10; ++i) {
            e[i] = expf(svs[i] - m);
            sum += e[i];
        }
        float inv = 1.f / sum;
        float rt = 0.f;
#pragma unroll
        for (int nn = 0; nn < 10; ++nn) rt = fmaf(gtss[nn][o], e[nn] * inv, rt);
        rtok[(size_t)b * 32 + o] = rt;
    }
}

// ---------------------------------------------------------------------------
// Stage 1: conv(7x7,s2,p3)+bias+relu+half-pool via MFMA (R14 exact).
// ---------------------------------------------------------------------------
#define PSTRIDE 120
#define PHALF (63 * PSTRIDE)
__global__ __launch_bounds__(512, 4) void conv_mfma(const float* __restrict__ img,
                                                    const unsigned int* __restrict__ wBu,
                                                    const float* __restrict__ cb,
                                                    float* __restrict__ pooledH) {
    __shared__ __align__(16) unsigned int patch[2 * PHALF];
    const int t = threadIdx.x;
    const int py = blockIdx.x, half = blockIdx.y, b = blockIdx.z;
    const int B = gridDim.z;
    const int lane = t & 63, wid = t >> 6;
    const int r16 = lane & 15, g = lane >> 4;
    const int Y0 = 32 * py + 16 * half - 3;

    const int xc0 = 2 * lane - 3;
    const int xc1 = 2 * lane + 125;
    const int a00 = max(xc0, 0);
    const int a01 = max(xc0 + 1, 0);
    const int a10 = min(xc1, 223);
    const int a11 = min(xc1 + 1, 223);
    const bool v00 = (xc0 >= 0);
    const bool v01 = (xc0 + 1 >= 0);
    const bool v10 = (xc1 <= 223);
    const bool v11 = (xc1 + 1 <= 223);
    const bool c1act = (lane < 52);

    const float* ib = img + (size_t)b * 3 * 224 * 224;

#pragma unroll
    for (int hb = 0; hb < 2; ++hb) {
        float g0[4], g1[4], g2[4], g3[4];
        int rr[4];
        bool rv[4];
#pragma unroll
        for (int i = 0; i < 4; ++i) {
            int r = wid + 8 * (hb * 4 + i);
            int c_ = (r >= 42) ? 2 : ((r >= 21) ? 1 : 0);
            int pr = r - 21 * c_;
            int iy = Y0 + pr;
            rv[i] = (r < 63) & (iy >= 0) & (iy < 224);
            int iyc = min(max(iy, 0), 223);
            const float* rp = ib + (c_ * 224 + iyc) * 224;
            rr[i] = r;
            g0[i] = rp[a00];
            g1[i] = rp[a01];
            g2[i] = rp[a10];
            g3[i] = rp[a11];
        }
#pragma unroll
        for (int i = 0; i < 4; ++i) {
            float f0 = (rv[i] && v00) ? g0[i] : 0.f;
            float f1 = (rv[i] && v01) ? g1[i] : 0.f;
            float f2_ = (rv[i] && v10) ? g2[i] : 0.f;
            float f3 = (rv[i] && v11) ? g3[i] : 0.f;
            if (rr[i] < 63) {
                unsigned int v01p = pack2(f0, f1);
                unsigned int v23p = pack2(f2_, f3);
                patch[rr[i] * PSTRIDE + lane] = v01p;
                if (lane >= 1) patch[PHALF + rr[i] * PSTRIDE + lane - 1] = v01p;
                if (c1act) {
                    patch[rr[i] * PSTRIDE + 64 + lane] = v23p;
                    patch[PHALF + rr[i] * PSTRIDE + 63 + lane] = v23p;
                }
            }
        }
    }

    bf16x8 bfrA[6], bfrB[6];
    int rowoff[6];
#pragma unroll
    for (int k = 0; k < 6; ++k) {
        int s = 4 * k + g;
        int c = s >> 3, ky = s & 7;
        int kyc = ky > 6 ? 6 : ky;
        rowoff[k] = c * 21 + kyc;
        union { uint4 q; bf16x8 v; } ua, ub;
        ua.q = *(const uint4*)(wBu + (s * 32 + r16) * 4);
        ub.q = *(const uint4*)(wBu + (s * 32 + r16 + 16) * 4);
        bfrA[k] = ua.v;
        bfrB[k] = ub.v;
    }
    const float biasA = cb[r16], biasB = cb[r16 + 16];

    __syncthreads();

    const int sel = r16 & 1;
    const unsigned int* pbase = patch + sel * PHALF;
    float accA[7], accB[7];
    int rb[6];
#pragma unroll
    for (int k = 0; k < 6; ++k) rb[k] = (rowoff[k] + 2 * wid) * PSTRIDE;

    for (int t7 = 0; t7 < 7; ++t7) {
        const int idx0 = 16 * t7 + r16 - sel;
        f32x4 C0 = {biasA, biasA, biasA, biasA};
        f32x4 C1 = {biasB, biasB, biasB, biasB};
#pragma unroll
        for (int k = 0; k < 6; ++k) {
            const uint2* ap2 = (const uint2*)(pbase + rb[k] + idx0);
            uint2 q0 = ap2[0];
            uint2 q1 = ap2[1];
            union { unsigned int u[4]; bf16x8 v; } ua;
            ua.u[0] = q0.x;
            ua.u[1] = q0.y;
            ua.u[2] = q1.x;
            ua.u[3] = q1.y;
            C0 = __builtin_amdgcn_mfma_f32_16x16x32_bf16(ua.v, bfrA[k], C0, 0, 0, 0);
            C1 = __builtin_amdgcn_mfma_f32_16x16x32_bf16(ua.v, bfrB[k], C1, 0, 0, 0);
        }
        float s0 = 0.f, s1 = 0.f;
#pragma unroll
        for (int r = 0; r < 4; ++r) {
            s0 += fmaxf(C0[r], 0.f);
            s1 += fmaxf(C1[r], 0.f);
        }
        accA[t7] = s0;
        accB[t7] = s1;
    }
#pragma unroll
    for (int p = 0; p < 7; ++p) {
        accA[p] += __shfl_xor(accA[p], 16);
        accA[p] += __shfl_xor(accA[p], 32);
        accB[p] += __shfl_xor(accB[p], 16);
        accB[p] += __shfl_xor(accB[p], 32);
    }
    __syncthreads();
    float* sw = (float*)patch;
    if (lane < 16) {
#pragma unroll
        for (int p = 0; p < 7; ++p) {
            sw[(wid * 7 + p) * 32 + lane] = accA[p];
            sw[(wid * 7 + p) * 32 + lane + 16] = accB[p];
        }
    }
    __syncthreads();
    if (t < 224) {
        int p = t >> 5, ch = t & 31;
        float s = 0.f;
#pragma unroll
        for (int w = 0; w < 8; ++w) s += sw[(w * 7 + p) * 32 + ch];
        pooledH[(size_t)(half * B + b) * 1568 + ch * 49 + py * 7 + p] = s * (1.f / 256.f);
    }
}

// ===========================================================================
// Tail phase bodies (shared by coop kernel and fallback kernels)
// ===========================================================================
static __device__ __forceinline__ void fc1_body(int blk, int t, const float* in,
                                                const float* w, const float* bias,
                                                float* out, int B) {
    const int lane = t & 63, wid = t >> 6;
    const int qg = blk & 31;
    const int bg = blk >> 5;
    const int b0 = bg * 8;
    const int o0 = (qg * 4 + wid) * 4;
    const float4* wp = (const float4*)w;
    const float4* xp0 = (const float4*)in;
    const float4* xp1 = xp0 + (size_t)B * 392;

    float acc[4][8];
#pragma unroll
    for (int oo = 0; oo < 4; ++oo)
#pragma unroll
        for (int r = 0; r < 8; ++r) acc[oo][r] = 0.f;

    for (int i = lane; i < 392; i += 64) {
        float4 wv[4];
#pragma unroll
        for (int oo = 0; oo < 4; ++oo) wv[oo] = wp[(size_t)(o0 + oo) * 392 + i];
#pragma unroll
        for (int r = 0; r < 8; ++r) {
            float4 a = xp0[(size_t)(b0 + r) * 392 + i];
            float4 c = xp1[(size_t)(b0 + r) * 392 + i];
            float4 xv = {a.x + c.x, a.y + c.y, a.z + c.z, a.w + c.w};
#pragma unroll
            for (int oo = 0; oo < 4; ++oo) {
                acc[oo][r] = fmaf(xv.x, wv[oo].x, acc[oo][r]);
                acc[oo][r] = fmaf(xv.y, wv[oo].y, acc[oo][r]);
                acc[oo][r] = fmaf(xv.z, wv[oo].z, acc[oo][r]);
                acc[oo][r] = fmaf(xv.w, wv[oo].w, acc[oo][r]);
            }
        }
    }
#pragma unroll
    for (int oo = 0; oo < 4; ++oo) {
        float v = 0.f;
#pragma unroll
        for (int r = 0; r < 8; ++r) {
            float s = acc[oo][r];
            s += __shfl_xor(s, 32);
            s += __shfl_xor(s, 16);
            s += __shfl_xor(s, 8);
            s += __shfl_xor(s, 4);
            s += __shfl_xor(s, 2);
            s += __shfl_xor(s, 1);
            if (lane == r) v = s;
        }
        if (lane < 8)
            out[(size_t)(b0 + lane) * 512 + o0 + oo] = fmaxf(v + bias[o0 + oo], 0.f);
    }
}

static __device__ __forceinline__ void vlm_body(int blk, int t, const float* h1,
                                                const float* w2, const float* b2,
                                                const int* tlen, const float* temb,
                                                const float* tw, const float* tb,
                                                const float* rtok, float* fused) {
    const int lane = t & 63, wid = t >> 6;
    const int ogq = blk % 48;
    const int bg = blk / 48;
    const int b0 = bg * 8;
    const int o0 = (ogq * 4 + wid) * 4;

    int rows[8];
#pragma unroll
    for (int r = 0; r < 8; ++r) {
        int v = tlen[b0 + r];
        rows[r] = min(max(v, 0), 9999);
    }
    const float4* wp = (const float4*)w2;
    const float4* xp = (const float4*)h1;
    const float4* wtp = (const float4*)tw;
    const float4* xtp = (const float4*)temb;

    float acc[4][8];
#pragma unroll
    for (int oo = 0; oo < 4; ++oo)
#pragma unroll
        for (int r = 0; r < 8; ++r) acc[oo][r] = 0.f;

#pragma unroll
    for (int ii = 0; ii < 2; ++ii) {
        int i = lane + (ii << 6);
        float4 wv[4];
#pragma unroll
        for (int oo = 0; oo < 4; ++oo) wv[oo] = wp[(size_t)(o0 + oo) * 128 + i];
#pragma unroll
        for (int r = 0; r < 8; ++r) {
            float4 xv = xp[(size_t)(b0 + r) * 128 + i];
#pragma unroll
            for (int oo = 0; oo < 4; ++oo) {
                acc[oo][r] = fmaf(xv.x, wv[oo].x, acc[oo][r]);
                acc[oo][r] = fmaf(xv.y, wv[oo].y, acc[oo][r]);
                acc[oo][r] = fmaf(xv.z, wv[oo].z, acc[oo][r]);
                acc[oo][r] = fmaf(xv.w, wv[oo].w, acc[oo][r]);
            }
        }
    }
    {
        float4 wv[4];
#pragma unroll
        for (int oo = 0; oo < 4; ++oo) wv[oo] = wtp[(size_t)(o0 + oo) * 64 + lane];
#pragma unroll
        for (int r = 0; r < 8; ++r) {
            float4 xv = xtp[(size_t)rows[r] * 64 + lane];
#pragma unroll
            for (int oo = 0; oo < 4; ++oo) {
                acc[oo][r] = fmaf(xv.x, wv[oo].x, acc[oo][r]);
                acc[oo][r] = fmaf(xv.y, wv[oo].y, acc[oo][r]);
                acc[oo][r] = fmaf(xv.z, wv[oo].z, acc[oo][r]);
                acc[oo][r] = fmaf(xv.w, wv[oo].w, acc[oo][r]);
            }
        }
    }
#pragma unroll
    for (int oo = 0; oo < 4; ++oo) {
        float v = 0.f;
#pragma unroll
        for (int r = 0; r < 8; ++r) {
            float s = acc[oo][r];
            s += __shfl_xor(s, 32);
            s += __shfl_xor(s, 16);
            s += __shfl_xor(s, 8);
            s += __shfl_xor(s, 4);
            s += __shfl_xor(s, 2);
            s += __shfl_xor(s, 1);
            if (lane == r) v = s;
        }
        int o = o0 + oo;
        if (lane < 8) {
            float add = (o < 32) ? rtok[(size_t)(b0 + lane) * 32 + o] : 0.f;
            fused[(size_t)(b0 + lane) * 768 + o] = v + b2[o] + tb[o] + add;
        }
    }
}

static __device__ __forceinline__ void head1_body(int blk, int t, const float* fused,
                                                  const float* gts, const float* w1,
                                                  const float* b1, float* h1T) {
    const int lane = t & 63, wid = t >> 6;
    const int ogq = blk % 48;
    const int bg = blk / 48;
    const int b0 = bg * 8;
    const int j = ogq >> 3;
    const int o0 = ogq * 16 + wid * 4;
    const float4* wp = (const float4*)w1;
    const float4* fp = (const float4*)fused;
    const float4* gp = (const float4*)gts;

    float acc[4][8];
#pragma unroll
    for (int oo = 0; oo < 4; ++oo)
#pragma unroll
        for (int r = 0; r < 8; ++r) acc[oo][r] = 0.f;

    for (int i = lane; i < 200; i += 64) {
        float4 wv[4];
#pragma unroll
        for (int oo = 0; oo < 4; ++oo) wv[oo] = wp[(size_t)(o0 + oo) * 200 + i];
#pragma unroll
        for (int r = 0; r < 8; ++r) {
            float4 xv = (i < 192) ? fp[(size_t)(b0 + r) * 192 + i]
                                  : gp[(size_t)(b0 + r) * 80 + j * 8 + (i - 192)];
#pragma unroll
            for (int oo = 0; oo < 4; ++oo) {
                acc[oo][r] = fmaf(xv.x, wv[oo].x, acc[oo][r]);
                acc[oo][r] = fmaf(xv.y, wv[oo].y, acc[oo][r]);
                acc[oo][r] = fmaf(xv.z, wv[oo].z, acc[oo][r]);
                acc[oo][r] = fmaf(xv.w, wv[oo].w, acc[oo][r]);
            }
        }
    }
#pragma unroll
    for (int oo = 0; oo < 4; ++oo) {
        float v = 0.f;
#pragma unroll
        for (int r = 0; r < 8; ++r) {
            float s = acc[oo][r];
            s += __shfl_xor(s, 32);
            s += __shfl_xor(s, 16);
            s += __shfl_xor(s, 8);
            s += __shfl_xor(s, 4);
            s += __shfl_xor(s, 2);
            s += __shfl_xor(s, 1);
            if (lane == r) v = s;
        }
        int o = o0 + oo;
        if (lane < 8) h1T[(size_t)o * 128 + b0 + lane] = fmaxf(v + b1[o], 0.f);
    }
}

// ---------------------------------------------------------------------------
// Cooperative TAIL: 512 blocks x 256 thr, launch_bounds(256,2) guarantees
// >=2 blocks/CU co-residency (512 <= 2*256 CUs). Phases 2/3 grid-stride 768.
// ---------------------------------------------------------------------------
__global__ __launch_bounds__(256, 2) void tail_k(
    const float* __restrict__ pooledH, const float* __restrict__ fc1w,
    const float* __restrict__ fc1b, float* __restrict__ h1fc,
    const float* __restrict__ w2v, const float* __restrict__ b2v,
    const int* __restrict__ tlen, const float* __restrict__ temb,
    const float* __restrict__ tw, const float* __restrict__ tb,
    const float* __restrict__ rtok, float* __restrict__ fused,
    const float* __restrict__ gts, const float* __restrict__ w1,
    const float* __restrict__ b1, float* __restrict__ h1T,
    const float* __restrict__ hw2, const float* __restrict__ hb2,
    float* __restrict__ h2T, const float* __restrict__ hw3,
    const float* __restrict__ hb3, float* __restrict__ out, int B) {
    cg::grid_group grid = cg::this_grid();
    const int t = threadIdx.x;
    const int blk = blockIdx.x;

    fc1_body(blk, t, pooledH, fc1w, fc1b, h1fc, B);
    __threadfence();
    grid.sync();

    for (int vb = blk; vb < 768; vb += 512)
        vlm_body(vb, t, h1fc, w2v, b2v, tlen, temb, tw, tb, rtok, fused);
    __threadfence();
    grid.sync();

    for (int vb = blk; vb < 768; vb += 512)
        head1_body(vb, t, fused, gts, w1, b1, h1T);
    __threadfence();
    grid.sync();

    if (blk < 192) {
        const int o2 = blk * 2 + (t >> 7);
        const int j = o2 >> 6;
        const int bb = t & 127;
        const float* wrow = hw2 + (size_t)o2 * 128;
        const float* xcol = h1T + (size_t)j * 128 * 128 + bb;
        float acc = hb2[o2];
#pragma unroll 16
        for (int k = 0; k < 128; ++k) acc = fmaf(xcol[k * 128], wrow[k], acc);
        h2T[(size_t)o2 * 128 + bb] = fmaxf(acc, 0.f);
    }
    __threadfence();
    grid.sync();

    if (blk < 80) {
        const int idx = blk * 2 + (t >> 7);
        const int jj = idx % 10;
        const int oo = idx / 10;
        const int bb = t & 127;
        float acc = 0.f;
        if (jj < 6) {
            const float* wrow = hw3 + (size_t)(jj * 16 + oo) * 64;
            const float* xcol = h2T + (size_t)jj * 64 * 128 + bb;
            acc = hb3[jj * 16 + oo];
#pragma unroll 16
            for (int k = 0; k < 64; ++k) acc = fmaf(xcol[k * 128], wrow[k], acc);
        }
        out[(size_t)bb * 160 + oo * 10 + jj] = acc;
    }
}

// ---------------------------------------------------------------------------
// Fallback standalone tail kernels (R14 proven) -- used if coop launch fails.
// ---------------------------------------------------------------------------
__global__ __launch_bounds__(256) void fc1_k(const float* __restrict__ in,
                                             const float* __restrict__ w,
                                             const float* __restrict__ bias,
                                             float* __restrict__ out, int B) {
    fc1_body(blockIdx.x, threadIdx.x, in, w, bias, out, B);
}

__global__ __launch_bounds__(256) void vlm_k(const float* __restrict__ h1,
                                             const float* __restrict__ w2,
                                             const float* __restrict__ b2,
                                             const int* __restrict__ tlen,
                                             const float* __restrict__ temb,
                                             const float* __restrict__ tw,
                                             const float* __restrict__ tb,
                                             const float* __restrict__ rtok,
                                             float* __restrict__ fused) {
    vlm_body(blockIdx.x, threadIdx.x, h1, w2, b2, tlen, temb, tw, tb, rtok, fused);
}

__global__ __launch_bounds__(256) void head1_k(const float* __restrict__ fused,
                                               const float* __restrict__ gts,
                                               const float* __restrict__ w1,
                                               const float* __restrict__ b1,
                                               float* __restrict__ h1T) {
    head1_body(blockIdx.x, threadIdx.x, fused, gts, w1, b1, h1T);
}

__global__ __launch_bounds__(128) void head2_k(const float* __restrict__ h1T,
                                               const float* __restrict__ w2,
                                               const float* __restrict__ b2,
                                               float* __restrict__ h2T) {
    const int o2 = blockIdx.x;
    const int j = o2 >> 6;
    const int b = threadIdx.x;
    const float* wrow = w2 + (size_t)o2 * 128;
    const float* xcol = h1T + (size_t)j * 128 * 128 + b;
    float acc = b2[o2];
#pragma unroll 16
    for (int k = 0; k < 128; ++k) acc = fmaf(xcol[k * 128], wrow[k], acc);
    h2T[(size_t)o2 * 128 + b] = fmaxf(acc, 0.f);
}

__global__ __launch_bounds__(128) void head3_k(const float* __restrict__ h2T,
                                               const float* __restrict__ w3,
                                               const float* __restrict__ b3,
                                               float* __restrict__ out) {
    const int jj = blockIdx.x % 10;
    const int oo = blockIdx.x / 10;
    const int b = threadIdx.x;
    float acc = 0.f;
    if (jj < 6) {
        const float* wrow = w3 + (size_t)(jj * 16 + oo) * 64;
        const float* xcol = h2T + (size_t)jj * 64 * 128 + b;
        acc = b3[jj * 16 + oo];
#pragma unroll 16
        for (int k = 0; k < 64; ++k) acc = fmaf(xcol[k * 128], wrow[k], acc);
    }
    out[(size_t)b * 160 + oo * 10 + jj] = acc;
}

// ---------------------------------------------------------------------------
extern "C" void kernel_launch(void* const* d_in, const int* in_sizes, int n_in,
                              void* d_out, int out_size, void* d_ws, size_t ws_size,
                              hipStream_t stream) {
    const float* images = (const float*)d_in[0];
    const int* tlen = (const int*)d_in[1];
    const float* nfeat = (const float*)d_in[2];
    const int* eidx = (const int*)d_in[3];
    const float* conv_w = (const float*)d_in[4];
    const float* conv_b = (const float*)d_in[5];
    const float* fc1w = (const float*)d_in[6];
    const float* fc1b = (const float*)d_in[7];
    const float* fc2w = (const float*)d_in[8];
    const float* fc2b = (const float*)d_in[9];
    const float* temb = (const float*)d_in[10];
    const float* tfw = (const float*)d_in[11];
    const float* tfb = (const float*)d_in[12];
    const float* e1w = (const float*)d_in[13];
    const float* e1b = (const float*)d_in[14];
    const float* e2w = (const float*)d_in[15];
    const float* e2b = (const float*)d_in[16];
    const float* gcw = (const float*)d_in[17];
    const float* gcb = (const float*)d_in[18];
    const float* lns = (const float*)d_in[19];
    const float* lnb = (const float*)d_in[20];
    const float* pjw = (const float*)d_in[21];
    const float* pjb = (const float*)d_in[22];
    const float* a1w = (const float*)d_in[23];
    const float* a1b = (const float*)d_in[24];
    const float* a2w = (const float*)d_in[25];
    const float* a2b = (const float*)d_in[26];
    const float* w1 = (const float*)d_in[27];
    const float* b1 = (const float*)d_in[28];
    const float* w2 = (const float*)d_in[29];
    const float* b2 = (const float*)d_in[30];
    const float* w3 = (const float*)d_in[31];
    const float* b3 = (const float*)d_in[32];

    const int B = in_sizes[0] / (3 * 224 * 224);  // 128

    float* ws = (float*)d_ws;
    unsigned short* wB = (unsigned short*)d_ws;     // 6144 bf16 (=3072 floats)
    float* pooledH = ws + 3072;                     // 2*B*1568 (dead after fc1)
    float* h1fc = pooledH + (size_t)2 * B * 1568;   // B*512
    float* fused = h1fc + (size_t)B * 512;          // B*768
    float* gts = fused + (size_t)B * 768;           // B*320
    float* rtok = gts + (size_t)B * 320;            // B*32
    float* h1T = pooledH;                           // 768*128 (aliases pooledH)
    float* h2T = pooledH + 98304;                   // 384*128 (aliases pooledH)
    float* outp = (float*)d_out;

    graph_wprep<<<B + 1, 640, 0, stream>>>(conv_w, wB, nfeat, eidx,
                                           e1w, e1b, e2w, e2b, gcw, gcb,
                                           lns, lnb, pjw, pjb, a1w, a1b,
                                           a2w, a2b, gts, rtok, B);
    conv_mfma<<<dim3(7, 2, B), 512, 0, stream>>>(images, (const unsigned int*)wB,
                                                 conv_b, pooledH);
    int Bv = B;
    void* args[] = {(void*)&pooledH, (void*)&fc1w, (void*)&fc1b, (void*)&h1fc,
                    (void*)&fc2w, (void*)&fc2b, (void*)&tlen, (void*)&temb,
                    (void*)&tfw, (void*)&tfb, (void*)&rtok, (void*)&fused,
                    (void*)&gts, (void*)&w1, (void*)&b1, (void*)&h1T,
                    (void*)&w2, (void*)&b2, (void*)&h2T, (void*)&w3,
                    (void*)&b3, (void*)&outp, (void*)&Bv};
    hipError_t cerr = hipLaunchCooperativeKernel((void*)tail_k, dim3(512),
                                                 dim3(256), args, 0, stream);
    if (cerr != hipSuccess) {
        // deterministic fallback: R14-proven split tail
        fc1_k<<<512, 256, 0, stream>>>(pooledH, fc1w, fc1b, h1fc, B);
        vlm_k<<<768, 256, 0, stream>>>(h1fc, fc2w, fc2b, tlen, temb, tfw, tfb,
                                       rtok, fused);
        head1_k<<<768, 256, 0, stream>>>(fused, gts, w1, b1, h1T);
        head2_k<<<384, 128, 0, stream>>>(h1T, w2, b2, h2T);
        head3_k<<<160, 128, 0, stream>>>(h2T, w3, b3, outp);
    }
}

// Round 17
// 119.662 us; speedup vs baseline: 4.1987x; 4.1987x over previous
//
#include <hip/hip_runtime.h>
#include <hip/hip_bf16.h>
#include <math.h>

typedef __attribute__((ext_vector_type(8))) short bf16x8;
typedef __attribute__((ext_vector_type(4))) float f32x4;

static __device__ __forceinline__ unsigned short f2bf(float f) {
    union { float f; unsigned int u; } x{f};
    unsigned int u = x.u;
    unsigned int r = (u + 0x7fffu + ((u >> 16) & 1u)) >> 16;  // RNE
    return (unsigned short)r;
}

static __device__ __forceinline__ unsigned int pack2(float f0, float f1) {
    __hip_bfloat162 h = __float22bfloat162_rn(float2{f0, f1});
    union { __hip_bfloat162 h; unsigned int u; } c{h};
    return c.u;
}

// ---------------------------------------------------------------------------
// Stage 0+4a: graph branch + wprep as block B (R13/R14 proven).
// ---------------------------------------------------------------------------
__global__ __launch_bounds__(640, 1) void graph_wprep(
    const float* __restrict__ conv_w, unsigned short* __restrict__ wB,
    const float* __restrict__ nfeat, const int* __restrict__ eidx,
    const float* __restrict__ e1w, const float* __restrict__ e1b,
    const float* __restrict__ e2w, const float* __restrict__ e2b,
    const float* __restrict__ gcw, const float* __restrict__ gcb,
    const float* __restrict__ lns, const float* __restrict__ lnb,
    const float* __restrict__ pjw, const float* __restrict__ pjb,
    const float* __restrict__ a1w, const float* __restrict__ a1b,
    const float* __restrict__ a2w, const float* __restrict__ a2b,
    float* __restrict__ gts_g, float* __restrict__ rtok, int B) {
    __shared__ __align__(16) float pool[8448];
    __shared__ __align__(16) float nf[10][20];
    __shared__ __align__(16) float xsA[10][64];
    __shared__ __align__(16) float xsB[10][64];
    __shared__ __align__(16) float nbs[10][64];
    __shared__ __align__(16) float gtss[10][32];
    __shared__ float svs[10];
    __shared__ int se[18], de[18];
    const int t = threadIdx.x;
    const int b = blockIdx.x;
    const int n = t >> 6, o = t & 63;

    if (b == B) {
        for (int idx = t; idx < 24 * 32 * 8; idx += 640) {
            int s = idx >> 8;
            int ch = (idx >> 3) & 31;
            int kx = idx & 7;
            int c = s >> 3, ky = s & 7;
            float v = 0.f;
            if (ky < 7 && kx < 7) v = conv_w[ch * 147 + c * 49 + ky * 7 + kx];
            wB[idx] = f2bf(v);
        }
        return;
    }

    if (t < 190) {
        int nn = t / 19, i = t - nn * 19;
        nf[nn][i] = nfeat[(size_t)(b * 10 + nn) * 19 + i];
    }
    if (t < 36) {
        if (t < 18) se[t] = eidx[b * 36 + t];
        else de[t - 18] = eidx[b * 36 + t];
    }
    float* e1wT = pool;
    float* e2wT = pool + 1280;
    for (int u = t; u < 1216; u += 640) {
        int oo = u / 19, k = u - oo * 19;
        e1wT[k * 64 + oo] = e1w[u];
    }
    for (int u = t; u < 4096; u += 640) {
        int oo = u >> 6, k = u & 63;
        e2wT[k * 65 + oo] = e2w[u];
    }
    __syncthreads();

    {
        float acc = e1b[o];
#pragma unroll
        for (int i = 0; i < 19; ++i) acc = fmaf(nf[n][i], e1wT[i * 64 + o], acc);
        xsB[n][o] = fmaxf(acc, 0.f);
    }
    {
        const float* xrow = &xsB[n][0];
        float s0 = 0, s1 = 0, s2 = 0, s3 = 0;
#pragma unroll
        for (int k = 0; k < 64; k += 4) {
            s0 = fmaf(xrow[k], e2wT[k * 65 + o], s0);
            s1 = fmaf(xrow[k + 1], e2wT[(k + 1) * 65 + o], s1);
            s2 = fmaf(xrow[k + 2], e2wT[(k + 2) * 65 + o], s2);
            s3 = fmaf(xrow[k + 3], e2wT[(k + 3) * 65 + o], s3);
        }
        xsA[n][o] = e2b[o] + ((s0 + s1) + (s2 + s3));
    }
    __syncthreads();

    float* src = &xsA[0][0];
    float* dst = &xsB[0][0];
    for (int l = 0; l < 3; ++l) {
        const float* gl = gcw + (size_t)l * 8192;
        for (int u = t; u < 8192; u += 640) {
            int oo = u >> 7, k = u & 127;
            pool[k * 65 + oo] = gl[u];
        }
        {
            float s = 0.f;
            int cnt = 0;
#pragma unroll
            for (int e = 0; e < 18; ++e) {
                bool m = (de[e] == n);
                float v = src[se[e] * 64 + o];
                s += m ? v : 0.f;
                cnt += m ? 1 : 0;
            }
            nbs[n][o] = s / (float)(cnt > 1 ? cnt : 1);
        }
        __syncthreads();
        {
            const float* xa = src + n * 64;
            const float* xb = &nbs[n][0];
            float s0 = 0, s1 = 0, s2 = 0, s3 = 0;
#pragma unroll
            for (int k = 0; k < 64; k += 4) {
                s0 = fmaf(xa[k], pool[k * 65 + o], s0);
                s1 = fmaf(xa[k + 1], pool[(k + 1) * 65 + o], s1);
                s2 = fmaf(xa[k + 2], pool[(k + 2) * 65 + o], s2);
                s3 = fmaf(xa[k + 3], pool[(k + 3) * 65 + o], s3);
            }
#pragma unroll
            for (int k = 0; k < 64; k += 4) {
                s0 = fmaf(xb[k], pool[(64 + k) * 65 + o], s0);
                s1 = fmaf(xb[k + 1], pool[(64 + k + 1) * 65 + o], s1);
                s2 = fmaf(xb[k + 2], pool[(64 + k + 2) * 65 + o], s2);
                s3 = fmaf(xb[k + 3], pool[(64 + k + 3) * 65 + o], s3);
            }
            float v = gcb[l * 64 + o] + ((s0 + s1) + (s2 + s3)) + xa[o];
            float mu = v;
            mu += __shfl_xor(mu, 32);
            mu += __shfl_xor(mu, 16);
            mu += __shfl_xor(mu, 8);
            mu += __shfl_xor(mu, 4);
            mu += __shfl_xor(mu, 2);
            mu += __shfl_xor(mu, 1);
            mu *= (1.f / 64.f);
            float d = v - mu;
            float vr = d * d;
            vr += __shfl_xor(vr, 32);
            vr += __shfl_xor(vr, 16);
            vr += __shfl_xor(vr, 8);
            vr += __shfl_xor(vr, 4);
            vr += __shfl_xor(vr, 2);
            vr += __shfl_xor(vr, 1);
            vr *= (1.f / 64.f);
            dst[n * 64 + o] =
                fmaxf(d / sqrtf(vr + 1e-5f) * lns[l * 64 + o] + lnb[l * 64 + o], 0.f);
        }
        __syncthreads();
        float* tmp = src;
        src = dst;
        dst = tmp;
    }

    float* pjwT = pool;
    float* a1wT = pool + 2112;
    for (int u = t; u < 2048; u += 640) {
        int oo = u >> 6, k = u & 63;
        pjwT[k * 33 + oo] = pjw[u];
    }
    for (int u = t; u < 512; u += 640) {
        int hh = u >> 5, k = u & 31;
        a1wT[k * 17 + hh] = a1w[u];
    }
    __syncthreads();

    if (o < 32) {
        const float* xrow = src + n * 64;
        float s0 = 0, s1 = 0, s2 = 0, s3 = 0;
#pragma unroll
        for (int k = 0; k < 64; k += 4) {
            s0 = fmaf(xrow[k], pjwT[k * 33 + o], s0);
            s1 = fmaf(xrow[k + 1], pjwT[(k + 1) * 33 + o], s1);
            s2 = fmaf(xrow[k + 2], pjwT[(k + 2) * 33 + o], s2);
            s3 = fmaf(xrow[k + 3], pjwT[(k + 3) * 33 + o], s3);
        }
        float gv = pjb[o] + ((s0 + s1) + (s2 + s3));
        gtss[n][o] = gv;
        gts_g[(size_t)b * 320 + n * 32 + o] = gv;
    }
    if (o < 16) {
        const float* xrow = &gtss[n][0];
        float s0 = 0, s1 = 0, s2 = 0, s3 = 0;
#pragma unroll
        for (int k = 0; k < 32; k += 4) {
            s0 = fmaf(xrow[k], a1wT[k * 17 + o], s0);
            s1 = fmaf(xrow[k + 1], a1wT[(k + 1) * 17 + o], s1);
            s2 = fmaf(xrow[k + 2], a1wT[(k + 2) * 17 + o], s2);
            s3 = fmaf(xrow[k + 3], a1wT[(k + 3) * 17 + o], s3);
        }
        float z = a1b[o] + ((s0 + s1) + (s2 + s3));
        float sc = tanhf(z) * a2w[o];
        sc += __shfl_xor(sc, 8);
        sc += __shfl_xor(sc, 4);
        sc += __shfl_xor(sc, 2);
        sc += __shfl_xor(sc, 1);
        if (o == 0) svs[n] = sc + a2b[0];
    }
    __syncthreads();

    if (n == 0 && o < 32) {
        float m = svs[0];
#pragma unroll
        for (int i = 1; i < 10; ++i) m = fmaxf(m, svs[i]);
        float e[10];
        float sum = 0.f;
#pragma unroll
        for (int i = 0; i < 10; ++i) {
            e[i] = expf(svs[i] - m);
            sum += e[i];
        }
        float inv = 1.f / sum;
        float rt = 0.f;
#pragma unroll
        for (int nn = 0; nn < 10; ++nn) rt = fmaf(gtss[nn][o], e[nn] * inv, rt);
        rtok[(size_t)b * 32 + o] = rt;
    }
}

// ---------------------------------------------------------------------------
// Stage 1: conv(7x7,s2,p3)+bias+relu+half-pool via MFMA (R14 exact).
// Dual shifted patch -> b64-aligned A-fragment reads. 59 KB LDS.
// ---------------------------------------------------------------------------
#define PSTRIDE 120
#define PHALF (63 * PSTRIDE)
__global__ __launch_bounds__(512, 4) void conv_mfma(const float* __restrict__ img,
                                                    const unsigned int* __restrict__ wBu,
                                                    const float* __restrict__ cb,
                                                    float* __restrict__ pooledH) {
    __shared__ __align__(16) unsigned int patch[2 * PHALF];
    const int t = threadIdx.x;
    const int py = blockIdx.x, half = blockIdx.y, b = blockIdx.z;
    const int B = gridDim.z;
    const int lane = t & 63, wid = t >> 6;
    const int r16 = lane & 15, g = lane >> 4;
    const int Y0 = 32 * py + 16 * half - 3;

    const int xc0 = 2 * lane - 3;
    const int xc1 = 2 * lane + 125;
    const int a00 = max(xc0, 0);
    const int a01 = max(xc0 + 1, 0);
    const int a10 = min(xc1, 223);
    const int a11 = min(xc1 + 1, 223);
    const bool v00 = (xc0 >= 0);
    const bool v01 = (xc0 + 1 >= 0);
    const bool v10 = (xc1 <= 223);
    const bool v11 = (xc1 + 1 <= 223);
    const bool c1act = (lane < 52);

    const float* ib = img + (size_t)b * 3 * 224 * 224;

#pragma unroll
    for (int hb = 0; hb < 2; ++hb) {
        float g0[4], g1[4], g2[4], g3[4];
        int rr[4];
        bool rv[4];
#pragma unroll
        for (int i = 0; i < 4; ++i) {
            int r = wid + 8 * (hb * 4 + i);
            int c_ = (r >= 42) ? 2 : ((r >= 21) ? 1 : 0);
            int pr = r - 21 * c_;
            int iy = Y0 + pr;
            rv[i] = (r < 63) & (iy >= 0) & (iy < 224);
            int iyc = min(max(iy, 0), 223);
            const float* rp = ib + (c_ * 224 + iyc) * 224;
            rr[i] = r;
            g0[i] = rp[a00];
            g1[i] = rp[a01];
            g2[i] = rp[a10];
            g3[i] = rp[a11];
        }
#pragma unroll
        for (int i = 0; i < 4; ++i) {
            float f0 = (rv[i] && v00) ? g0[i] : 0.f;
            float f1 = (rv[i] && v01) ? g1[i] : 0.f;
            float f2_ = (rv[i] && v10) ? g2[i] : 0.f;
            float f3 = (rv[i] && v11) ? g3[i] : 0.f;
            if (rr[i] < 63) {
                unsigned int v01p = pack2(f0, f1);
                unsigned int v23p = pack2(f2_, f3);
                patch[rr[i] * PSTRIDE + lane] = v01p;
                if (lane >= 1) patch[PHALF + rr[i] * PSTRIDE + lane - 1] = v01p;
                if (c1act) {
                    patch[rr[i] * PSTRIDE + 64 + lane] = v23p;
                    patch[PHALF + rr[i] * PSTRIDE + 63 + lane] = v23p;
                }
            }
        }
    }

    bf16x8 bfrA[6], bfrB[6];
    int rowoff[6];
#pragma unroll
    for (int k = 0; k < 6; ++k) {
        int s = 4 * k + g;
        int c = s >> 3, ky = s & 7;
        int kyc = ky > 6 ? 6 : ky;
        rowoff[k] = c * 21 + kyc;
        union { uint4 q; bf16x8 v; } ua, ub;
        ua.q = *(const uint4*)(wBu + (s * 32 + r16) * 4);
        ub.q = *(const uint4*)(wBu + (s * 32 + r16 + 16) * 4);
        bfrA[k] = ua.v;
        bfrB[k] = ub.v;
    }
    const float biasA = cb[r16], biasB = cb[r16 + 16];

    __syncthreads();

    const int sel = r16 & 1;
    const unsigned int* pbase = patch + sel * PHALF;
    float accA[7], accB[7];
    int rb[6];
#pragma unroll
    for (int k = 0; k < 6; ++k) rb[k] = (rowoff[k] + 2 * wid) * PSTRIDE;

    for (int t7 = 0; t7 < 7; ++t7) {
        const int idx0 = 16 * t7 + r16 - sel;
        f32x4 C0 = {biasA, biasA, biasA, biasA};
        f32x4 C1 = {biasB, biasB, biasB, biasB};
#pragma unroll
        for (int k = 0; k < 6; ++k) {
            const uint2* ap2 = (const uint2*)(pbase + rb[k] + idx0);
            uint2 q0 = ap2[0];
            uint2 q1 = ap2[1];
            union { unsigned int u[4]; bf16x8 v; } ua;
            ua.u[0] = q0.x;
            ua.u[1] = q0.y;
            ua.u[2] = q1.x;
            ua.u[3] = q1.y;
            C0 = __builtin_amdgcn_mfma_f32_16x16x32_bf16(ua.v, bfrA[k], C0, 0, 0, 0);
            C1 = __builtin_amdgcn_mfma_f32_16x16x32_bf16(ua.v, bfrB[k], C1, 0, 0, 0);
        }
        float s0 = 0.f, s1 = 0.f;
#pragma unroll
        for (int r = 0; r < 4; ++r) {
            s0 += fmaxf(C0[r], 0.f);
            s1 += fmaxf(C1[r], 0.f);
        }
        accA[t7] = s0;
        accB[t7] = s1;
    }
#pragma unroll
    for (int p = 0; p < 7; ++p) {
        accA[p] += __shfl_xor(accA[p], 16);
        accA[p] += __shfl_xor(accA[p], 32);
        accB[p] += __shfl_xor(accB[p], 16);
        accB[p] += __shfl_xor(accB[p], 32);
    }
    __syncthreads();
    float* sw = (float*)patch;
    if (lane < 16) {
#pragma unroll
        for (int p = 0; p < 7; ++p) {
            sw[(wid * 7 + p) * 32 + lane] = accA[p];
            sw[(wid * 7 + p) * 32 + lane + 16] = accB[p];
        }
    }
    __syncthreads();
    if (t < 224) {
        int p = t >> 5, ch = t & 31;
        float s = 0.f;
#pragma unroll
        for (int w = 0; w < 8; ++w) s += sw[(w * 7 + p) * 32 + ch];
        pooledH[(size_t)(half * B + b) * 1568 + ch * 49 + py * 7 + p] = s * (1.f / 256.f);
    }
}

// ---------------------------------------------------------------------------
// Stage 2: fc1 (B,1568)->(B,512), relu; sums the two pool halves. [R14]
// ---------------------------------------------------------------------------
__global__ __launch_bounds__(256) void fc1_k(const float* __restrict__ in,
                                             const float* __restrict__ w,
                                             const float* __restrict__ bias,
                                             float* __restrict__ out, int B) {
    const int t = threadIdx.x, lane = t & 63, wid = t >> 6;
    const int qg = blockIdx.x & 31;
    const int bg = blockIdx.x >> 5;
    const int b0 = bg * 8;
    const int o0 = (qg * 4 + wid) * 4;
    const float4* wp = (const float4*)w;
    const float4* xp0 = (const float4*)in;
    const float4* xp1 = xp0 + (size_t)B * 392;

    float acc[4][8];
#pragma unroll
    for (int oo = 0; oo < 4; ++oo)
#pragma unroll
        for (int r = 0; r < 8; ++r) acc[oo][r] = 0.f;

    for (int i = lane; i < 392; i += 64) {
        float4 wv[4];
#pragma unroll
        for (int oo = 0; oo < 4; ++oo) wv[oo] = wp[(size_t)(o0 + oo) * 392 + i];
#pragma unroll
        for (int r = 0; r < 8; ++r) {
            float4 a = xp0[(size_t)(b0 + r) * 392 + i];
            float4 c = xp1[(size_t)(b0 + r) * 392 + i];
            float4 xv = {a.x + c.x, a.y + c.y, a.z + c.z, a.w + c.w};
#pragma unroll
            for (int oo = 0; oo < 4; ++oo) {
                acc[oo][r] = fmaf(xv.x, wv[oo].x, acc[oo][r]);
                acc[oo][r] = fmaf(xv.y, wv[oo].y, acc[oo][r]);
                acc[oo][r] = fmaf(xv.z, wv[oo].z, acc[oo][r]);
                acc[oo][r] = fmaf(xv.w, wv[oo].w, acc[oo][r]);
            }
        }
    }
#pragma unroll
    for (int oo = 0; oo < 4; ++oo) {
        float v = 0.f;
#pragma unroll
        for (int r = 0; r < 8; ++r) {
            float s = acc[oo][r];
            s += __shfl_xor(s, 32);
            s += __shfl_xor(s, 16);
            s += __shfl_xor(s, 8);
            s += __shfl_xor(s, 4);
            s += __shfl_xor(s, 2);
            s += __shfl_xor(s, 1);
            if (lane == r) v = s;
        }
        if (lane < 8)
            out[(size_t)(b0 + lane) * 512 + o0 + oo] = fmaxf(v + bias[o0 + oo], 0.f);
    }
}

// ---------------------------------------------------------------------------
// Stage 3: fused = img_fc2(h1) + text_fc(temb[len]) + biases (+ rtok) [R14]
// ---------------------------------------------------------------------------
__global__ __launch_bounds__(256) void vlm_k(const float* __restrict__ h1,
                                             const float* __restrict__ w2,
                                             const float* __restrict__ b2,
                                             const int* __restrict__ tlen,
                                             const float* __restrict__ temb,
                                             const float* __restrict__ tw,
                                             const float* __restrict__ tb,
                                             const float* __restrict__ rtok,
                                             float* __restrict__ fused) {
    const int t = threadIdx.x, lane = t & 63, wid = t >> 6;
    const int ogq = blockIdx.x % 48;
    const int bg = blockIdx.x / 48;
    const int b0 = bg * 8;
    const int o0 = (ogq * 4 + wid) * 4;

    int rows[8];
#pragma unroll
    for (int r = 0; r < 8; ++r) {
        int v = tlen[b0 + r];
        rows[r] = min(max(v, 0), 9999);
    }
    const float4* wp = (const float4*)w2;
    const float4* xp = (const float4*)h1;
    const float4* wtp = (const float4*)tw;
    const float4* xtp = (const float4*)temb;

    float acc[4][8];
#pragma unroll
    for (int oo = 0; oo < 4; ++oo)
#pragma unroll
        for (int r = 0; r < 8; ++r) acc[oo][r] = 0.f;

#pragma unroll
    for (int ii = 0; ii < 2; ++ii) {
        int i = lane + (ii << 6);
        float4 wv[4];
#pragma unroll
        for (int oo = 0; oo < 4; ++oo) wv[oo] = wp[(size_t)(o0 + oo) * 128 + i];
#pragma unroll
        for (int r = 0; r < 8; ++r) {
            float4 xv = xp[(size_t)(b0 + r) * 128 + i];
#pragma unroll
            for (int oo = 0; oo < 4; ++oo) {
                acc[oo][r] = fmaf(xv.x, wv[oo].x, acc[oo][r]);
                acc[oo][r] = fmaf(xv.y, wv[oo].y, acc[oo][r]);
                acc[oo][r] = fmaf(xv.z, wv[oo].z, acc[oo][r]);
                acc[oo][r] = fmaf(xv.w, wv[oo].w, acc[oo][r]);
            }
        }
    }
    {
        float4 wv[4];
#pragma unroll
        for (int oo = 0; oo < 4; ++oo) wv[oo] = wtp[(size_t)(o0 + oo) * 64 + lane];
#pragma unroll
        for (int r = 0; r < 8; ++r) {
            float4 xv = xtp[(size_t)rows[r] * 64 + lane];
#pragma unroll
            for (int oo = 0; oo < 4; ++oo) {
                acc[oo][r] = fmaf(xv.x, wv[oo].x, acc[oo][r]);
                acc[oo][r] = fmaf(xv.y, wv[oo].y, acc[oo][r]);
                acc[oo][r] = fmaf(xv.z, wv[oo].z, acc[oo][r]);
                acc[oo][r] = fmaf(xv.w, wv[oo].w, acc[oo][r]);
            }
        }
    }
#pragma unroll
    for (int oo = 0; oo < 4; ++oo) {
        float v = 0.f;
#pragma unroll
        for (int r = 0; r < 8; ++r) {
            float s = acc[oo][r];
            s += __shfl_xor(s, 32);
            s += __shfl_xor(s, 16);
            s += __shfl_xor(s, 8);
            s += __shfl_xor(s, 4);
            s += __shfl_xor(s, 2);
            s += __shfl_xor(s, 1);
            if (lane == r) v = s;
        }
        int o = o0 + oo;
        if (lane < 8) {
            float add = (o < 32) ? rtok[(size_t)(b0 + lane) * 32 + o] : 0.f;
            fused[(size_t)(b0 + lane) * 768 + o] = v + b2[o] + tb[o] + add;
        }
    }
}

// ---------------------------------------------------------------------------
// Stage 4b: head layer 1: comb(800) -> 768, relu -> h1T[o][b]. [R14]
// ---------------------------------------------------------------------------
__global__ __launch_bounds__(256) void head1_k(const float* __restrict__ fused,
                                               const float* __restrict__ gts,
                                               const float* __restrict__ w1,
                                               const float* __restrict__ b1,
                                               float* __restrict__ h1T) {
    const int t = threadIdx.x, lane = t & 63, wid = t >> 6;
    const int ogq = blockIdx.x % 48;
    const int bg = blockIdx.x / 48;
    const int b0 = bg * 8;
    const int j = ogq >> 3;
    const int o0 = ogq * 16 + wid * 4;
    const float4* wp = (const float4*)w1;
    const float4* fp = (const float4*)fused;
    const float4* gp = (const float4*)gts;

    float acc[4][8];
#pragma unroll
    for (int oo = 0; oo < 4; ++oo)
#pragma unroll
        for (int r = 0; r < 8; ++r) acc[oo][r] = 0.f;

    for (int i = lane; i < 200; i += 64) {
        float4 wv[4];
#pragma unroll
        for (int oo = 0; oo < 4; ++oo) wv[oo] = wp[(size_t)(o0 + oo) * 200 + i];
#pragma unroll
        for (int r = 0; r < 8; ++r) {
            float4 xv = (i < 192) ? fp[(size_t)(b0 + r) * 192 + i]
                                  : gp[(size_t)(b0 + r) * 80 + j * 8 + (i - 192)];
#pragma unroll
            for (int oo = 0; oo < 4; ++oo) {
                acc[oo][r] = fmaf(xv.x, wv[oo].x, acc[oo][r]);
                acc[oo][r] = fmaf(xv.y, wv[oo].y, acc[oo][r]);
                acc[oo][r] = fmaf(xv.z, wv[oo].z, acc[oo][r]);
                acc[oo][r] = fmaf(xv.w, wv[oo].w, acc[oo][r]);
            }
        }
    }
#pragma unroll
    for (int oo = 0; oo < 4; ++oo) {
        float v = 0.f;
#pragma unroll
        for (int r = 0; r < 8; ++r) {
            float s = acc[oo][r];
            s += __shfl_xor(s, 32);
            s += __shfl_xor(s, 16);
            s += __shfl_xor(s, 8);
            s += __shfl_xor(s, 4);
            s += __shfl_xor(s, 2);
            s += __shfl_xor(s, 1);
            if (lane == r) v = s;
        }
        int o = o0 + oo;
        if (lane < 8) h1T[(size_t)o * 128 + b0 + lane] = fmaxf(v + b1[o], 0.f);
    }
}

// ---------------------------------------------------------------------------
// Stage 4c: head layer 2: 128 -> 64 per joint, relu -> h2T[o2][b]. [R14]
// ---------------------------------------------------------------------------
__global__ __launch_bounds__(128) void head2_k(const float* __restrict__ h1T,
                                               const float* __restrict__ w2,
                                               const float* __restrict__ b2,
                                               float* __restrict__ h2T) {
    const int o2 = blockIdx.x;
    const int j = o2 >> 6;
    const int b = threadIdx.x;
    const float* wrow = w2 + (size_t)o2 * 128;
    const float* xcol = h1T + (size_t)j * 128 * 128 + b;
    float acc = b2[o2];
#pragma unroll 16
    for (int k = 0; k < 128; ++k) acc = fmaf(xcol[k * 128], wrow[k], acc);
    h2T[(size_t)o2 * 128 + b] = fmaxf(acc, 0.f);
}

// ---------------------------------------------------------------------------
// Stage 4d: head layer 3 + transpose + pad -> out (B,16,10). [R14]
// ---------------------------------------------------------------------------
__global__ __launch_bounds__(128) void head3_k(const float* __restrict__ h2T,
                                               const float* __restrict__ w3,
                                               const float* __restrict__ b3,
                                               float* __restrict__ out) {
    const int jj = blockIdx.x % 10;
    const int oo = blockIdx.x / 10;
    const int b = threadIdx.x;
    float acc = 0.f;
    if (jj < 6) {
        const float* wrow = w3 + (size_t)(jj * 16 + oo) * 64;
        const float* xcol = h2T + (size_t)jj * 64 * 128 + b;
        acc = b3[jj * 16 + oo];
#pragma unroll 16
        for (int k = 0; k < 64; ++k) acc = fmaf(xcol[k * 128], wrow[k], acc);
    }
    out[(size_t)b * 160 + oo * 10 + jj] = acc;
}

// ---------------------------------------------------------------------------
extern "C" void kernel_launch(void* const* d_in, const int* in_sizes, int n_in,
                              void* d_out, int out_size, void* d_ws, size_t ws_size,
                              hipStream_t stream) {
    const float* images = (const float*)d_in[0];
    const int* tlen = (const int*)d_in[1];
    const float* nfeat = (const float*)d_in[2];
    const int* eidx = (const int*)d_in[3];
    const float* conv_w = (const float*)d_in[4];
    const float* conv_b = (const float*)d_in[5];
    const float* fc1w = (const float*)d_in[6];
    const float* fc1b = (const float*)d_in[7];
    const float* fc2w = (const float*)d_in[8];
    const float* fc2b = (const float*)d_in[9];
    const float* temb = (const float*)d_in[10];
    const float* tfw = (const float*)d_in[11];
    const float* tfb = (const float*)d_in[12];
    const float* e1w = (const float*)d_in[13];
    const float* e1b = (const float*)d_in[14];
    const float* e2w = (const float*)d_in[15];
    const float* e2b = (const float*)d_in[16];
    const float* gcw = (const float*)d_in[17];
    const float* gcb = (const float*)d_in[18];
    const float* lns = (const float*)d_in[19];
    const float* lnb = (const float*)d_in[20];
    const float* pjw = (const float*)d_in[21];
    const float* pjb = (const float*)d_in[22];
    const float* a1w = (const float*)d_in[23];
    const float* a1b = (const float*)d_in[24];
    const float* a2w = (const float*)d_in[25];
    const float* a2b = (const float*)d_in[26];
    const float* w1 = (const float*)d_in[27];
    const float* b1 = (const float*)d_in[28];
    const float* w2 = (const float*)d_in[29];
    const float* b2 = (const float*)d_in[30];
    const float* w3 = (const float*)d_in[31];
    const float* b3 = (const float*)d_in[32];

    const int B = in_sizes[0] / (3 * 224 * 224);  // 128

    float* ws = (float*)d_ws;
    unsigned short* wB = (unsigned short*)d_ws;     // 6144 bf16 (=3072 floats)
    float* pooledH = ws + 3072;                     // 2*B*1568 (dead after fc1)
    float* h1fc = pooledH + (size_t)2 * B * 1568;   // B*512
    float* fused = h1fc + (size_t)B * 512;          // B*768
    float* gts = fused + (size_t)B * 768;           // B*320
    float* rtok = gts + (size_t)B * 320;            // B*32
    float* h1T = pooledH;                           // 768*128 (aliases pooledH)
    float* h2T = pooledH + 98304;                   // 384*128 (aliases pooledH)

    graph_wprep<<<B + 1, 640, 0, stream>>>(conv_w, wB, nfeat, eidx,
                                           e1w, e1b, e2w, e2b, gcw, gcb,
                                           lns, lnb, pjw, pjb, a1w, a1b,
                                           a2w, a2b, gts, rtok, B);
    conv_mfma<<<dim3(7, 2, B), 512, 0, stream>>>(images, (const unsigned int*)wB,
                                                 conv_b, pooledH);
    fc1_k<<<512, 256, 0, stream>>>(pooledH, fc1w, fc1b, h1fc, B);
    vlm_k<<<768, 256, 0, stream>>>(h1fc, fc2w, fc2b, tlen, temb, tfw, tfb,
                                   rtok, fused);
    head1_k<<<768, 256, 0, stream>>>(fused, gts, w1, b1, h1T);
    head2_k<<<384, 128, 0, stream>>>(h1T, w2, b2, h2T);
    head3_k<<<160, 128, 0, stream>>>(h2T, w3, b3, (float*)d_out);
}